// Round 2
// baseline (233.871 us; speedup 1.0000x reference)
//
#include <hip/hip_runtime.h>
#include <hip/hip_bf16.h>

// Problem constants
#define BB 2
#define SS 2048
#define DD 64
#define HH 8
#define HD 512            // HH*DD
#define SCALE 0.125f      // 1/sqrt(64)

typedef __bf16 bf16;
typedef __attribute__((ext_vector_type(8))) __bf16 bf16x8;
typedef __attribute__((ext_vector_type(4))) float floatx4;

__device__ __forceinline__ floatx4 mfma16(bf16x8 a, bf16x8 b, floatx4 c) {
    return __builtin_amdgcn_mfma_f32_16x16x32_bf16(a, b, c, 0, 0, 0);
}

// Load 8 consecutive elements starting at element index idx (idx % 4 == 0),
// interpreting the buffer as fp32 (f32!=0) or bf16 (f32==0). Returns bf16x8.
__device__ __forceinline__ bf16x8 load8(const void* base, size_t idx, int f32) {
    if (f32) {
        const float* p = (const float*)base + idx;
        const float4 a = *reinterpret_cast<const float4*>(p);
        const float4 b = *reinterpret_cast<const float4*>(p + 4);
        bf16x8 r;
        r[0] = (bf16)a.x; r[1] = (bf16)a.y; r[2] = (bf16)a.z; r[3] = (bf16)a.w;
        r[4] = (bf16)b.x; r[5] = (bf16)b.y; r[6] = (bf16)b.z; r[7] = (bf16)b.w;
        return r;
    }
    return *reinterpret_cast<const bf16x8*>((const bf16*)base + idx);
}

__device__ __forceinline__ float load1(const void* base, int idx, int f32) {
    return f32 ? ((const float*)base)[idx] : (float)((const bf16*)base)[idx];
}

// ---------------------------------------------------------------------------
// Kernel 0: dtype detection. Interpret q's first 8192 halfwords as bf16 bit
// patterns. Real bf16 N(0,1) data never reaches |v|>=128 (exp field >= 134);
// fp32 mantissa halves hit it with p~0.48/elem. Deterministic given inputs.
// ---------------------------------------------------------------------------
__global__ __launch_bounds__(64) void detect_kernel(const unsigned short* __restrict__ q,
                                                    int* __restrict__ flag) {
    int hit = 0;
    for (int i = threadIdx.x; i < 8192; i += 64) {
        const unsigned short u = q[i];
        const int e = (u >> 7) & 0xFF;
        if (e >= 134) hit = 1;
    }
    const unsigned long long m = __ballot(hit);
    if (threadIdx.x == 0) *flag = (m != 0ull) ? 1 : 0;
}

// ---------------------------------------------------------------------------
// Kernel 1: QKV projection (MFMA) + RoPE (q,k) + fp32 norms + V transpose.
// One wave per (weight w, batch b, 16-row tile st, head h).
// A[m][k]: m=lane&15, k=quad*8+j.  B[k][n]=W[n][k]: n=lane&15.
// C/D: col=lane&15, row=quad*4+reg.
// ---------------------------------------------------------------------------
__global__ __launch_bounds__(64) void proj_rope_kernel(
    const void* __restrict__ q, const void* __restrict__ Wq,
    const void* __restrict__ Wk, const void* __restrict__ Wv,
    bf16* __restrict__ qh, bf16* __restrict__ kh, bf16* __restrict__ vt,
    float* __restrict__ qn, float* __restrict__ kn,
    const int* __restrict__ flagp)
{
    const int f32  = *flagp;
    const int lane = threadIdx.x;
    const int l16  = lane & 15;
    const int quad = lane >> 4;

    int id = blockIdx.x;                 // ((w*BB + b)*(SS/16) + st)*HH + h
    const int h  = id % HH; id /= HH;
    const int st = id % (SS / 16); id /= (SS / 16);
    const int b  = id % BB; id /= BB;
    const int w  = id;                   // 0=q, 1=k, 2=v
    const int s0 = st * 16;

    const void* W = (w == 0) ? Wq : (w == 1) ? Wk : Wv;

    const size_t qrow = ((size_t)b * SS + s0 + l16) * DD;
    bf16x8 a0 = load8(q, qrow + quad * 8, f32);
    bf16x8 a1 = load8(q, qrow + quad * 8 + 32, f32);

    floatx4 cv[4];
#pragma unroll
    for (int t = 0; t < 4; ++t) {
        const size_t wrow = (size_t)(h * 64 + t * 16 + l16) * DD;
        bf16x8 b0 = load8(W, wrow + quad * 8, f32);
        bf16x8 b1 = load8(W, wrow + quad * 8 + 32, f32);
        floatx4 acc = {0.f, 0.f, 0.f, 0.f};
        acc = mfma16(a0, b0, acc);
        acc = mfma16(a1, b1, acc);
        cv[t] = acc;
    }

    const size_t bh = (size_t)b * HH + h;

    if (w < 2) {
        bf16*  dst  = (w == 0) ? qh : kh;
        float* ndst = (w == 0) ? qn : kn;
        float nacc[4] = {0.f, 0.f, 0.f, 0.f};
#pragma unroll
        for (int t = 0; t < 4; ++t) {
            const int d    = t * 16 + l16;
            const int twoi = d & ~1;
            const float freq = powf(10000.0f, -(float)twoi * (1.0f / 64.0f));
            const bool odd = (d & 1);
#pragma unroll
            for (int r = 0; r < 4; ++r) {
                float v = cv[t][r];
                float partner = __shfl_xor(v, 1);
                const int srow = s0 + quad * 4 + r;
                float sn, cs;
                sincosf((float)srow * freq, &sn, &cs);   // precise range reduction
                float res = odd ? (partner * sn + v * cs)
                                : (v * cs - partner * sn);
                nacc[r] += res * res;                    // fp32 norm pre-rounding
                dst[(bh * SS + srow) * DD + d] = (bf16)res;
            }
        }
#pragma unroll
        for (int off = 1; off < 16; off <<= 1)
#pragma unroll
            for (int r = 0; r < 4; ++r)
                nacc[r] += __shfl_xor(nacc[r], off);
        if (l16 == 0)
#pragma unroll
            for (int r = 0; r < 4; ++r)
                ndst[bh * SS + s0 + quad * 4 + r] = nacc[r];
    } else {
        // V: no rope, store transposed (B,H,D,S) so PV B-frags are k-contig
#pragma unroll
        for (int t = 0; t < 4; ++t) {
            const int d = t * 16 + l16;
#pragma unroll
            for (int r = 0; r < 4; ++r) {
                const int srow = s0 + quad * 4 + r;
                vt[(bh * DD + d) * SS + srow] = (bf16)cv[t][r];
            }
        }
    }
}

// ---------------------------------------------------------------------------
// Kernel 2: causal distance-kernel attention. One wave per 16-query tile.
// scores = exp(-gamma*SCALE*dist); no softmax normalization -> plain accum.
// ---------------------------------------------------------------------------
#define PSTR 48   // LDS row stride (shorts): 96B, 16B-aligned for ds_read_b128

__global__ __launch_bounds__(64) void attn_kernel(
    const bf16* __restrict__ qh, const bf16* __restrict__ kh,
    const bf16* __restrict__ vt, const float* __restrict__ qn,
    const float* __restrict__ kn, const void* __restrict__ gamma,
    bf16* __restrict__ outh, const int* __restrict__ flagp)
{
    __shared__ bf16 P[16 * PSTR];
    const int f32  = *flagp;
    const int lane = threadIdx.x;
    const int l16  = lane & 15;
    const int quad = lane >> 4;

    int id = blockIdx.x;
    const int qt = id % (SS / 16); id /= (SS / 16);
    const int h  = id % HH; id /= HH;
    const int b  = id;
    const int s0 = qt * 16;
    const size_t bh = (size_t)b * HH + h;

    const float gs = load1(gamma, h, f32) * SCALE;

    const bf16* qbase = qh + (bh * SS + s0 + l16) * DD;
    bf16x8 aq0 = *reinterpret_cast<const bf16x8*>(qbase + quad * 8);
    bf16x8 aq1 = *reinterpret_cast<const bf16x8*>(qbase + quad * 8 + 32);

    float qn_r[4];
#pragma unroll
    for (int r = 0; r < 4; ++r) qn_r[r] = qn[bh * SS + s0 + quad * 4 + r];

    floatx4 acc[4];
#pragma unroll
    for (int nb = 0; nb < 4; ++nb) acc[nb] = (floatx4){0.f, 0.f, 0.f, 0.f};

    const int nchunks = (s0 + 16 + 31) / 32;
    for (int c = 0; c < nchunks; ++c) {
        const int t0 = c * 32;
#pragma unroll
        for (int sub = 0; sub < 2; ++sub) {
            const int n0 = t0 + sub * 16;
            const bf16* krow = kh + (bh * SS + n0 + l16) * DD;
            bf16x8 bk0 = *reinterpret_cast<const bf16x8*>(krow + quad * 8);
            bf16x8 bk1 = *reinterpret_cast<const bf16x8*>(krow + quad * 8 + 32);
            floatx4 qk = {0.f, 0.f, 0.f, 0.f};
            qk = mfma16(aq0, bk0, qk);
            qk = mfma16(aq1, bk1, qk);
            const float knv = kn[bh * SS + n0 + l16];
            const int tcol = n0 + l16;
#pragma unroll
            for (int r = 0; r < 4; ++r) {
                const int srow = s0 + quad * 4 + r;
                float dist = fmaxf(qn_r[r] - 2.0f * qk[r] + knv, 0.0f);
                float p = (tcol <= srow) ? __expf(-gs * dist) : 0.0f;
                P[(quad * 4 + r) * PSTR + sub * 16 + l16] = (bf16)p;
            }
        }
        __syncthreads();   // C-layout -> A-layout via LDS
        bf16x8 ap = *reinterpret_cast<const bf16x8*>(&P[l16 * PSTR + quad * 8]);
#pragma unroll
        for (int nb = 0; nb < 4; ++nb) {
            const bf16* vrow = vt + (bh * DD + nb * 16 + l16) * SS + t0 + quad * 8;
            bf16x8 bv = *reinterpret_cast<const bf16x8*>(vrow);
            acc[nb] = mfma16(ap, bv, acc[nb]);
        }
        __syncthreads();
    }

#pragma unroll
    for (int nb = 0; nb < 4; ++nb)
#pragma unroll
        for (int r = 0; r < 4; ++r)
            outh[((size_t)b * SS + s0 + quad * 4 + r) * HD + h * 64 + nb * 16 + l16]
                = (bf16)acc[nb][r];
}

// ---------------------------------------------------------------------------
// Kernel 3: output projection (4096x512)@(512x64)^T.
// ---------------------------------------------------------------------------
__global__ __launch_bounds__(64) void outproj_kernel(
    const bf16* __restrict__ outh, const void* __restrict__ Wo,
    void* __restrict__ out, const int* __restrict__ flagp)
{
    const int f32  = *flagp;
    const int lane = threadIdx.x;
    const int l16  = lane & 15;
    const int quad = lane >> 4;
    const int ct = blockIdx.x & 3;
    const int rt = blockIdx.x >> 2;

    const bf16* arow = outh + ((size_t)rt * 16 + l16) * HD;
    const size_t brow = (size_t)(ct * 16 + l16) * HD;
    floatx4 acc = {0.f, 0.f, 0.f, 0.f};
#pragma unroll
    for (int kk = 0; kk < HD; kk += 32) {
        bf16x8 a  = *reinterpret_cast<const bf16x8*>(arow + kk + quad * 8);
        bf16x8 bb = load8(Wo, brow + kk + quad * 8, f32);
        acc = mfma16(a, bb, acc);
    }
#pragma unroll
    for (int r = 0; r < 4; ++r) {
        const size_t o = ((size_t)rt * 16 + quad * 4 + r) * DD + ct * 16 + l16;
        if (f32) ((float*)out)[o] = acc[r];
        else     ((bf16*)out)[o]  = (bf16)acc[r];
    }
}

// ---------------------------------------------------------------------------
extern "C" void kernel_launch(void* const* d_in, const int* in_sizes, int n_in,
                              void* d_out, int out_size, void* d_ws, size_t ws_size,
                              hipStream_t stream) {
    const void* q     = d_in[0];
    const void* Wq    = d_in[1];
    const void* Wk    = d_in[2];
    const void* Wv    = d_in[3];
    const void* Wo    = d_in[4];
    const void* gamma = d_in[5];

    char* ws = (char*)d_ws;
    // NE = B*H*S*D = 2,097,152 elems = 4 MiB bf16 each
    bf16*  qh   = (bf16*)(ws);
    bf16*  kh   = (bf16*)(ws + 4194304);
    bf16*  vt   = (bf16*)(ws + 8388608);
    bf16*  outh = (bf16*)(ws + 12582912);
    float* qn   = (float*)(ws + 16777216);
    float* kn   = (float*)(ws + 16908288);
    int*   flag = (int*)  (ws + 17039360);

    detect_kernel<<<dim3(1), dim3(64), 0, stream>>>((const unsigned short*)q, flag);
    proj_rope_kernel<<<dim3(3 * BB * (SS / 16) * HH), dim3(64), 0, stream>>>(
        q, Wq, Wk, Wv, qh, kh, vt, qn, kn, flag);
    attn_kernel<<<dim3(BB * HH * (SS / 16)), dim3(64), 0, stream>>>(
        qh, kh, vt, qn, kn, gamma, outh, flag);
    outproj_kernel<<<dim3((BB * SS / 16) * 4), dim3(64), 0, stream>>>(
        outh, Wo, d_out, flag);
}

// Round 3
// 202.492 us; speedup vs baseline: 1.1550x; 1.1550x over previous
//
#include <hip/hip_runtime.h>
#include <hip/hip_bf16.h>

// Problem constants
#define BB 2
#define SS 2048
#define DD 64
#define HH 8
#define HD 512            // HH*DD
#define SCALE 0.125f      // 1/sqrt(64)

typedef __bf16 bf16;
typedef __attribute__((ext_vector_type(4))) __bf16 bf16x4;
typedef __attribute__((ext_vector_type(8))) __bf16 bf16x8;
typedef __attribute__((ext_vector_type(4))) float floatx4;

#define SLOTSTRIDE 2097152   // BB*SS*HD floats per split-K partial slot

__device__ __forceinline__ floatx4 mfma16(bf16x8 a, bf16x8 b, floatx4 c) {
    return __builtin_amdgcn_mfma_f32_16x16x32_bf16(a, b, c, 0, 0, 0);
}

// Load 8 consecutive elements at element index idx (idx%4==0), interpreting
// the buffer as fp32 (f32!=0) or bf16 (f32==0). Returns bf16x8.
__device__ __forceinline__ bf16x8 load8(const void* base, size_t idx, int f32) {
    if (f32) {
        const float* p = (const float*)base + idx;
        const float4 a = *reinterpret_cast<const float4*>(p);
        const float4 b = *reinterpret_cast<const float4*>(p + 4);
        bf16x8 r;
        r[0] = (bf16)a.x; r[1] = (bf16)a.y; r[2] = (bf16)a.z; r[3] = (bf16)a.w;
        r[4] = (bf16)b.x; r[5] = (bf16)b.y; r[6] = (bf16)b.z; r[7] = (bf16)b.w;
        return r;
    }
    return *reinterpret_cast<const bf16x8*>((const bf16*)base + idx);
}

__device__ __forceinline__ float load1(const void* base, int idx, int f32) {
    return f32 ? ((const float*)base)[idx] : (float)((const bf16*)base)[idx];
}

// ---------------------------------------------------------------------------
// Kernel 0: dtype detection. bf16 N(0,1) never has |v|>=128 (exp>=134);
// fp32-mantissa halfwords hit that in ~48% of elements.
// ---------------------------------------------------------------------------
__global__ __launch_bounds__(64) void detect_kernel(const unsigned short* __restrict__ q,
                                                    int* __restrict__ flag) {
    int hit = 0;
    for (int i = threadIdx.x; i < 8192; i += 64) {
        const unsigned short u = q[i];
        if (((u >> 7) & 0xFF) >= 134) hit = 1;
    }
    const unsigned long long m = __ballot(hit);
    if (threadIdx.x == 0) *flag = (m != 0ull) ? 1 : 0;
}

// ---------------------------------------------------------------------------
// Kernel 1: QKV projection (MFMA) + RoPE via HW v_sin/v_cos + fp32 norms +
// vectorized V transpose (C-frag rows are 4 consecutive s -> 8B stores).
// ---------------------------------------------------------------------------
__global__ __launch_bounds__(64) void proj_rope_kernel(
    const void* __restrict__ q, const void* __restrict__ Wq,
    const void* __restrict__ Wk, const void* __restrict__ Wv,
    bf16* __restrict__ qh, bf16* __restrict__ kh, bf16* __restrict__ vt,
    float* __restrict__ qn, float* __restrict__ kn,
    const int* __restrict__ flagp)
{
    const int f32  = *flagp;
    const int lane = threadIdx.x;
    const int l16  = lane & 15;
    const int quad = lane >> 4;

    int id = blockIdx.x;                 // ((w*BB + b)*(SS/16) + st)*HH + h
    const int h  = id % HH; id /= HH;
    const int st = id % (SS / 16); id /= (SS / 16);
    const int b  = id % BB; id /= BB;
    const int w  = id;                   // 0=q, 1=k, 2=v
    const int s0 = st * 16;

    const void* W = (w == 0) ? Wq : (w == 1) ? Wk : Wv;

    const size_t qrow = ((size_t)b * SS + s0 + l16) * DD;
    bf16x8 a0 = load8(q, qrow + quad * 8, f32);
    bf16x8 a1 = load8(q, qrow + quad * 8 + 32, f32);

    floatx4 cv[4];
#pragma unroll
    for (int t = 0; t < 4; ++t) {
        const size_t wrow = (size_t)(h * 64 + t * 16 + l16) * DD;
        bf16x8 b0 = load8(W, wrow + quad * 8, f32);
        bf16x8 b1 = load8(W, wrow + quad * 8 + 32, f32);
        floatx4 acc = {0.f, 0.f, 0.f, 0.f};
        acc = mfma16(a0, b0, acc);
        acc = mfma16(a1, b1, acc);
        cv[t] = acc;
    }

    const size_t bh = (size_t)b * HH + h;

    if (w < 2) {
        bf16*  dst  = (w == 0) ? qh : kh;
        float* ndst = (w == 0) ? qn : kn;
        float nacc[4] = {0.f, 0.f, 0.f, 0.f};
#pragma unroll
        for (int t = 0; t < 4; ++t) {
            const int d    = t * 16 + l16;
            const int twoi = d & ~1;
            // freq/(2*pi) = 10000^(-twoi/64) / (2*pi), via v_exp
            const float frev = __builtin_amdgcn_exp2f(
                -(float)twoi * (13.2877123795f / 64.0f)) * 0.15915494309f;
            const bool odd = (d & 1);
#pragma unroll
            for (int r = 0; r < 4; ++r) {
                float v = cv[t][r];
                float partner = __shfl_xor(v, 1);
                const int srow = s0 + quad * 4 + r;
                float rev = (float)srow * frev;       // revolutions
                rev -= floorf(rev);
                float sn = __builtin_amdgcn_sinf(rev);
                float cs = __builtin_amdgcn_cosf(rev);
                float res = odd ? (partner * sn + v * cs)
                                : (v * cs - partner * sn);
                nacc[r] += res * res;                 // fp32 norm pre-rounding
                dst[(bh * SS + srow) * DD + d] = (bf16)res;
            }
        }
#pragma unroll
        for (int off = 1; off < 16; off <<= 1)
#pragma unroll
            for (int r = 0; r < 4; ++r)
                nacc[r] += __shfl_xor(nacc[r], off);
        if (l16 == 0)
#pragma unroll
            for (int r = 0; r < 4; ++r)
                ndst[bh * SS + s0 + quad * 4 + r] = nacc[r];
    } else {
        // V transposed (B,H,D,S); C-frag regs 0..3 are s=quad*4+0..3 -> 8B store
#pragma unroll
        for (int t = 0; t < 4; ++t) {
            const int d = t * 16 + l16;
            bf16x4 pv;
#pragma unroll
            for (int r = 0; r < 4; ++r) pv[r] = (bf16)cv[t][r];
            *reinterpret_cast<bf16x4*>(vt + (bh * DD + d) * SS + s0 + quad * 4) = pv;
        }
    }
}

// ---------------------------------------------------------------------------
// Kernel 2: causal distance-kernel attention, split-K along keys.
// One wave per (b,h,qt,slot); slot covers keys [slot<<ksh, (slot+1)<<ksh).
// Unnormalized scores -> partial PV sums are exact; fp32 partials per slot.
// K/kn prefetched one chunk ahead to shorten the exposed latency chain.
// ---------------------------------------------------------------------------
#define PSTR 40   // LDS row stride in shorts: 80B. 16B-aligned b128 reads,
                  // write conflicts 2-way (free) instead of 4-way at 48.

__global__ __launch_bounds__(64, 4) void attn_kernel(
    const bf16* __restrict__ qh, const bf16* __restrict__ kh,
    const bf16* __restrict__ vt, const float* __restrict__ qn,
    const float* __restrict__ kn, const void* __restrict__ gamma,
    float* __restrict__ partial, const int* __restrict__ flagp, int ksh)
{
    __shared__ bf16 P[16 * PSTR];
    const int f32  = *flagp;
    const int lane = threadIdx.x;
    const int l16  = lane & 15;
    const int quad = lane >> 4;

    int id = blockIdx.x;
    const int qt   = id & 127; id >>= 7;
    const int slot = id & 3;   id >>= 2;
    const int h    = id % HH;
    const int b    = id / HH;
    const int s0   = qt * 16;
    const int tb   = slot << ksh;
    const int te   = min(s0 + 16, tb + (1 << ksh));
    if (tb >= te) return;
    const size_t bh = (size_t)b * HH + h;

    const float gs = load1(gamma, h, f32) * SCALE;

    const bf16* qbase = qh + (bh * SS + s0 + l16) * DD;
    bf16x8 aq0 = *reinterpret_cast<const bf16x8*>(qbase + quad * 8);
    bf16x8 aq1 = *reinterpret_cast<const bf16x8*>(qbase + quad * 8 + 32);

    float qn_r[4];
#pragma unroll
    for (int r = 0; r < 4; ++r) qn_r[r] = qn[bh * SS + s0 + quad * 4 + r];

    floatx4 acc[4];
#pragma unroll
    for (int nb = 0; nb < 4; ++nb) acc[nb] = (floatx4){0.f, 0.f, 0.f, 0.f};

    const int nch = (te - tb + 31) >> 5;

    // prefetch chunk 0: K rows + kn
    bf16x8 kc[4]; float knc[2];
#pragma unroll
    for (int sub = 0; sub < 2; ++sub) {
        const bf16* krow = kh + (bh * SS + tb + sub * 16 + l16) * DD;
        kc[sub * 2]     = *reinterpret_cast<const bf16x8*>(krow + quad * 8);
        kc[sub * 2 + 1] = *reinterpret_cast<const bf16x8*>(krow + quad * 8 + 32);
        knc[sub] = kn[bh * SS + tb + sub * 16 + l16];
    }

    int t0 = tb;
    for (int c = 0; c < nch; ++c, t0 += 32) {
        // V loads for current chunk (used at end -> long time to complete)
        bf16x8 vv[4];
#pragma unroll
        for (int nb = 0; nb < 4; ++nb)
            vv[nb] = *reinterpret_cast<const bf16x8*>(
                vt + (bh * DD + nb * 16 + l16) * SS + t0 + quad * 8);

        floatx4 qk[2];
#pragma unroll
        for (int sub = 0; sub < 2; ++sub) {
            floatx4 z = {0.f, 0.f, 0.f, 0.f};
            z = mfma16(aq0, kc[sub * 2], z);
            z = mfma16(aq1, kc[sub * 2 + 1], z);
            qk[sub] = z;
        }
        const float kn0 = knc[0], kn1 = knc[1];

        // prefetch next chunk's K while we do exp/LDS
        bf16x8 kc2[4]; float knc2[2];
        if (c + 1 < nch) {
#pragma unroll
            for (int sub = 0; sub < 2; ++sub) {
                const bf16* krow = kh + (bh * SS + t0 + 32 + sub * 16 + l16) * DD;
                kc2[sub * 2]     = *reinterpret_cast<const bf16x8*>(krow + quad * 8);
                kc2[sub * 2 + 1] = *reinterpret_cast<const bf16x8*>(krow + quad * 8 + 32);
                knc2[sub] = kn[bh * SS + t0 + 32 + sub * 16 + l16];
            }
        }

#pragma unroll
        for (int sub = 0; sub < 2; ++sub) {
            const float knv = sub ? kn1 : kn0;
            const int tcol = t0 + sub * 16 + l16;
#pragma unroll
            for (int r = 0; r < 4; ++r) {
                const int srow = s0 + quad * 4 + r;
                float dist = fmaxf(qn_r[r] - 2.0f * qk[sub][r] + knv, 0.0f);
                float p = (tcol <= srow) ? __expf(-gs * dist) : 0.0f;
                P[(quad * 4 + r) * PSTR + sub * 16 + l16] = (bf16)p;
            }
        }
        __syncthreads();   // C-layout -> A-layout via LDS (single wave)
        bf16x8 ap = *reinterpret_cast<const bf16x8*>(&P[l16 * PSTR + quad * 8]);
#pragma unroll
        for (int nb = 0; nb < 4; ++nb) acc[nb] = mfma16(ap, vv[nb], acc[nb]);
        __syncthreads();

        if (c + 1 < nch) {
#pragma unroll
            for (int i = 0; i < 4; ++i) kc[i] = kc2[i];
            knc[0] = knc2[0]; knc[1] = knc2[1];
        }
    }

    float* pb = partial + (size_t)slot * SLOTSTRIDE
              + ((size_t)b * SS + s0) * HD + h * 64;
#pragma unroll
    for (int nb = 0; nb < 4; ++nb)
#pragma unroll
        for (int r = 0; r < 4; ++r)
            pb[(quad * 4 + r) * HD + nb * 16 + l16] = acc[nb][r];
}

// ---------------------------------------------------------------------------
// Kernel 3: fused split-K reduce + output projection (4096x512)@(512x64)^T.
// ---------------------------------------------------------------------------
__global__ __launch_bounds__(64) void outproj_kernel(
    const float* __restrict__ partial, const void* __restrict__ Wo,
    void* __restrict__ out, const int* __restrict__ flagp, int ksh)
{
    const int f32  = *flagp;
    const int lane = threadIdx.x;
    const int l16  = lane & 15;
    const int quad = lane >> 4;
    const int ct = blockIdx.x & 3;
    const int rt = blockIdx.x >> 2;

    const int g0 = rt * 16;              // global row (b*SS + s)
    const int s0 = g0 & (SS - 1);
    const int nact = (s0 + 16 + (1 << ksh) - 1) >> ksh;

    const float* prow = partial + (size_t)(g0 + l16) * HD;
    const size_t brow = (size_t)(ct * 16 + l16) * HD;
    floatx4 acc = {0.f, 0.f, 0.f, 0.f};
#pragma unroll 4
    for (int kk = 0; kk < HD; kk += 32) {
        const float* pp = prow + kk + quad * 8;
        float4 u0 = *reinterpret_cast<const float4*>(pp);
        float4 u1 = *reinterpret_cast<const float4*>(pp + 4);
        for (int s = 1; s < nact; ++s) {
            const float* ps = pp + (size_t)s * SLOTSTRIDE;
            const float4 w0 = *reinterpret_cast<const float4*>(ps);
            const float4 w1 = *reinterpret_cast<const float4*>(ps + 4);
            u0.x += w0.x; u0.y += w0.y; u0.z += w0.z; u0.w += w0.w;
            u1.x += w1.x; u1.y += w1.y; u1.z += w1.z; u1.w += w1.w;
        }
        bf16x8 a;
        a[0] = (bf16)u0.x; a[1] = (bf16)u0.y; a[2] = (bf16)u0.z; a[3] = (bf16)u0.w;
        a[4] = (bf16)u1.x; a[5] = (bf16)u1.y; a[6] = (bf16)u1.z; a[7] = (bf16)u1.w;
        bf16x8 bb = load8(Wo, brow + kk + quad * 8, f32);
        acc = mfma16(a, bb, acc);
    }
#pragma unroll
    for (int r = 0; r < 4; ++r) {
        const size_t o = (size_t)(g0 + quad * 4 + r) * DD + ct * 16 + l16;
        if (f32) ((float*)out)[o] = acc[r];
        else     ((bf16*)out)[o]  = (bf16)acc[r];
    }
}

// ---------------------------------------------------------------------------
extern "C" void kernel_launch(void* const* d_in, const int* in_sizes, int n_in,
                              void* d_out, int out_size, void* d_ws, size_t ws_size,
                              hipStream_t stream) {
    const void* q     = d_in[0];
    const void* Wq    = d_in[1];
    const void* Wk    = d_in[2];
    const void* Wv    = d_in[3];
    const void* Wo    = d_in[4];
    const void* gamma = d_in[5];

    char* ws = (char*)d_ws;
    bf16*  qh      = (bf16*)(ws);                    // 4 MiB
    bf16*  kh      = (bf16*)(ws + 4194304);          // 4 MiB
    bf16*  vt      = (bf16*)(ws + 8388608);          // 4 MiB
    float* qn      = (float*)(ws + 12582912);        // 128 KiB
    float* kn      = (float*)(ws + 12713984);        // 128 KiB
    int*   flag    = (int*)  (ws + 12845056);
    float* partial = (float*)(ws + 13631488);        // nslot x 8 MiB

    // split-K tier by available workspace: 4 / 2 / 1 slots
    int ksh = 11;
    if (ws_size >= 13631488ull + 4ull * 8388608ull)      ksh = 9;
    else if (ws_size >= 13631488ull + 2ull * 8388608ull) ksh = 10;

    detect_kernel<<<dim3(1), dim3(64), 0, stream>>>((const unsigned short*)q, flag);
    proj_rope_kernel<<<dim3(3 * BB * (SS / 16) * HH), dim3(64), 0, stream>>>(
        q, Wq, Wk, Wv, qh, kh, vt, qn, kn, flag);
    attn_kernel<<<dim3(BB * HH * 4 * (SS / 16)), dim3(64), 0, stream>>>(
        qh, kh, vt, qn, kn, gamma, partial, flag, ksh);
    outproj_kernel<<<dim3((BB * SS / 16) * 4), dim3(64), 0, stream>>>(
        partial, Wo, d_out, flag, ksh);
}